// Round 16
// baseline (35.533 us; speedup 1.0000x reference)
//
#include <hip/hip_runtime.h>

// SSIM loss, N=64 images, 1 ch, 384x384 f32, 7x7 box, VALID -> 378x378. out = -mean(S).
//
// R16: SHUFFLE-FREE register walker.
// Model (fits all 15 rounds): __shfl_down = ds_bpermute on the per-CU LDS pipe
// shared by 4 SIMDs; at 24 shuffles/step it saturates, so occupancy (R6/7/13/14),
// batching (R10), prefetch depth (R12) and VALU cuts (R15) were all neutral,
// while shuffle-count changes moved time 1:1 (R13: 1.33x shuffles -> 1.32x time;
// R5->R8: 30->24 -> -6%). Fix: lane owns output cols 6l..6l+5 but LOADS cols
// 6l..6l+11 (overlap with neighbor; same cache lines), so horizontal 7-tap
// windows are computed fully in-lane. Zero cross-lane ops in the hot loop.
//  - vertical sums per col: {sx, sy, sxy, su=sxx+syy} (merged at accumulation)
//  - no row history: old row RELOADED via a 2-step-ahead pipe (L1/L2 hit,
//    ~1400 cy cover; R6's failed reload had 1-step cover AND was shuffle-bound)
//  - ping-pong new/old buffers via 2-step unrolled body: no pipe-copy movs
//  - rows: 27 bands x 14 = 378 exactly -> no row masking; lane 63 masked only
//  - f32x2 packed column math (v_pk_*); h-chains scalar
//  - two-kernel deterministic reduction

constexpr int IND   = 384;
constexpr int OUTD  = 378;
constexpr int RB    = 14;            // output rows per band
constexpr int BANDS = OUTD / RB;     // 27
constexpr int CPL   = 6;             // output cols per lane
constexpr int SPAN  = 12;            // input cols per lane

using f32x2 = __attribute__((ext_vector_type(2))) float;
#define FMA2(a, b, c) __builtin_elementwise_fma((a), (b), (c))

__global__ __launch_bounds__(64, 2)
void ssim_band(const float* __restrict__ X, const float* __restrict__ Y,
               const float* __restrict__ MX, float* __restrict__ blocksum)
{
    const int band = blockIdx.x;
    const int n    = blockIdx.y;
    const int lane = threadIdx.x;
    int cL = lane * CPL;                       // input cols cL..cL+11
    if (cL > IND - SPAN) cL = IND - SPAN;      // lane 63: clamp (outputs masked)
    const int r0 = band * RB;                  // rows r0..r0+19 all <= 383

    const float* __restrict__ Xp = X + (size_t)n * (IND * IND) + cL;
    const float* __restrict__ Yp = Y + (size_t)n * (IND * IND) + cL;

    // vertical sums over 12 cols, packed
    f32x2 sx[6] = {}, sy[6] = {}, sxy[6] = {}, su[6] = {};
    // ping-pong row buffers (new rows, old rows)
    f32x2 nax[6], nay[6], nbx[6], nby[6];
    f32x2 oax[6], oay[6], obx[6], oby[6];

#define LOADROW(DX, DY, R) {                                                  \
    const float* _px = Xp + (size_t)(R) * IND;                                \
    const float* _py = Yp + (size_t)(R) * IND;                                \
    DX[0] = *(const f32x2*)_px;        DX[1] = *(const f32x2*)(_px + 2);      \
    DX[2] = *(const f32x2*)(_px + 4);  DX[3] = *(const f32x2*)(_px + 6);      \
    DX[4] = *(const f32x2*)(_px + 8);  DX[5] = *(const f32x2*)(_px + 10);     \
    DY[0] = *(const f32x2*)_py;        DY[1] = *(const f32x2*)(_py + 2);      \
    DY[2] = *(const f32x2*)(_py + 4);  DY[3] = *(const f32x2*)(_py + 6);      \
    DY[4] = *(const f32x2*)(_py + 8);  DY[5] = *(const f32x2*)(_py + 10); }

#define ACC(RX, RY) {                                                         \
    _Pragma("unroll")                                                         \
    for (int g = 0; g < 6; ++g) {                                             \
        f32x2 x = RX[g], y = RY[g];                                           \
        sx[g] += x;  sy[g] += y;                                              \
        sxy[g] = FMA2(x, y, sxy[g]);                                          \
        su[g]  = FMA2(x, x, FMA2(y, y, su[g]));                               \
    } }

#define SUB(RX, RY) {                                                         \
    _Pragma("unroll")                                                         \
    for (int g = 0; g < 6; ++g) {                                             \
        f32x2 x = RX[g], y = RY[g];                                           \
        sx[g] -= x;  sy[g] -= y;                                              \
        sxy[g] = FMA2(-x, y, sxy[g]);                                         \
        su[g]  = FMA2(-x, x, FMA2(-y, y, su[g]));                             \
    } }

    // ---- prologue: sums over rows r0..r0+5; pipes primed ----
    LOADROW(oax, oay, r0 + 0)          // old rows r0, r0+1 (steps 0,1)
    LOADROW(obx, oby, r0 + 1)
    ACC(oax, oay)
    ACC(obx, oby)
#pragma unroll
    for (int k = 2; k < 6; ++k) {      // transient rows via na buffer
        LOADROW(nax, nay, r0 + k)
        ACC(nax, nay)
    }
    LOADROW(nax, nay, r0 + 6)          // new rows r0+6, r0+7 (steps 0,1)
    LOADROW(nbx, nby, r0 + 7)

    const float m   = MX[n];
    const float c1s = (0.01f * m) * (0.01f * m);
    const float c2s = (0.03f * m) * (0.03f * m);
    const float k1  = 2401.0f * c1s;     // 49^2 * C1
    const float k2  = 2401.0f * c2s;
    const f32x2 K1  = {k1, k1};
    const f32x2 K2  = {k2, k2};
    const f32x2 CN  = {49.0f / 48.0f, 49.0f / 48.0f};
    const f32x2 CN2 = {2.0f * 49.0f / 48.0f, 2.0f * 49.0f / 48.0f};
    const f32x2 TWO = {2.0f, 2.0f};
    const f32x2 F49 = {49.0f, 49.0f};

    const bool valid = (lane < 63);
    float partial = 0.f;

    // scalar element view of f32x2[6] (c literal 0..11)
#define EL(S, c) (((c) & 1) ? S[(c) >> 1].y : S[(c) >> 1].x)

    // in-lane sliding 7-tap over own 12 values -> 6 windows
#define HS(S, O) {                                                            \
    float _t = ((EL(S,0) + EL(S,1)) + (EL(S,2) + EL(S,3)))                    \
             + ((EL(S,4) + EL(S,5)) + EL(S,6));                               \
    O[0] = _t;                                                                \
    _t += EL(S,7)  - EL(S,0);  O[1] = _t;                                     \
    _t += EL(S,8)  - EL(S,1);  O[2] = _t;                                     \
    _t += EL(S,9)  - EL(S,2);  O[3] = _t;                                     \
    _t += EL(S,10) - EL(S,3);  O[4] = _t;                                     \
    _t += EL(S,11) - EL(S,4);  O[5] = _t; }

    // One step s: NA holds row r0+s+6, OA holds row r0+s. Consume both,
    // reload NA <- row r0+s+8 (used at s+2), OA <- row r0+s+2 (used at s+2).
#define STEP(NAX, NAY, OAX, OAY, OLDR, NEWR) {                                \
        ACC(NAX, NAY)                                                         \
        float t1[6], t2[6], t5[6], t34[6];                                    \
        HS(sx,  t1) HS(sy,  t2) HS(sxy, t5) HS(su, t34)                       \
        SUB(OAX, OAY)                                                         \
        { int _r = (OLDR); LOADROW(OAX, OAY, _r) }                            \
        { int _r = (NEWR); if (_r > IND - 1) _r = IND - 1;                    \
          LOADROW(NAX, NAY, _r) }                                             \
        if (valid) {                                                          \
            _Pragma("unroll")                                                 \
            for (int g = 0; g < 3; ++g) {                                     \
                f32x2 T1  = {t1[2*g],  t1[2*g+1]};                            \
                f32x2 T2  = {t2[2*g],  t2[2*g+1]};                            \
                f32x2 T5  = {t5[2*g],  t5[2*g+1]};                            \
                f32x2 T34 = {t34[2*g], t34[2*g+1]};                           \
                f32x2 pxy = T1 * T2;                                          \
                f32x2 ss  = FMA2(T1, T1, T2 * T2);                            \
                f32x2 A1  = FMA2(TWO, pxy, K1);                               \
                f32x2 B1  = ss + K1;                                          \
                f32x2 A2  = FMA2(CN2, FMA2(F49, T5, -pxy), K2);               \
                f32x2 B2  = FMA2(CN,  FMA2(F49, T34, -ss), K2);               \
                f32x2 num = A1 * A2;                                          \
                f32x2 den = B1 * B2;                                          \
                partial += __fdividef(num.x, den.x)                           \
                         + __fdividef(num.y, den.y);                          \
            }                                                                 \
        }                                                                     \
    }

#pragma unroll 1                       // rolled: 2-step body stays I$-resident
    for (int ii = 0; ii < RB / 2; ++ii) {
        const int s0 = 2 * ii, s1 = 2 * ii + 1;
        STEP(nax, nay, oax, oay, r0 + s0 + 2, r0 + s0 + 8)   // even step
        STEP(nbx, nby, obx, oby, r0 + s1 + 2, r0 + s1 + 8)   // odd step
    }
#undef STEP
#undef HS
#undef EL
#undef SUB
#undef ACC
#undef LOADROW

    // ---- wave reduction (deterministic; only place with shuffles) ----
#pragma unroll
    for (int off = 32; off; off >>= 1) partial += __shfl_down(partial, off);
    if (lane == 0) blocksum[(size_t)n * BANDS + band] = partial;
}

__global__ __launch_bounds__(256)
void ssim_reduce(const float* __restrict__ blocksum, float* __restrict__ out,
                 int nblocks, float inv_npix)
{
    const int tid = threadIdx.x;
    float s = 0.f;
    for (int i = tid; i < nblocks; i += 256) s += blocksum[i];
#pragma unroll
    for (int off = 32; off; off >>= 1) s += __shfl_down(s, off);
    __shared__ float ws[4];
    if ((tid & 63) == 0) ws[tid >> 6] = s;
    __syncthreads();
    if (tid == 0) out[0] = -(ws[0] + ws[1] + ws[2] + ws[3]) * inv_npix;
}

extern "C" void kernel_launch(void* const* d_in, const int* in_sizes, int n_in,
                              void* d_out, int out_size, void* d_ws, size_t ws_size,
                              hipStream_t stream)
{
    const float* X  = (const float*)d_in[0];
    const float* Y  = (const float*)d_in[1];
    // d_in[2] = norm (unused by reference), d_in[4] = w (ones/49, baked in)
    const float* MX = (const float*)d_in[3];

    const int N       = in_sizes[3];             // 64
    const int nblocks = N * BANDS;               // 1728

    float* bs = (float*)d_ws;

    dim3 grid(BANDS, N);
    ssim_band<<<grid, 64, 0, stream>>>(X, Y, MX, bs);

    const float inv_npix = 1.0f / ((float)N * OUTD * OUTD);
    ssim_reduce<<<1, 256, 0, stream>>>(bs, (float*)d_out, nblocks, inv_npix);
}